// Round 6
// baseline (1967.189 us; speedup 1.0000x reference)
//
#include <hip/hip_runtime.h>

// KAN forward: 3 layers of [deg-3 B-spline basis (64 bases) -> einsum 'bik,ijk->bj'].
// Only 4 basis values are nonzero per point => 4-tap gather per (i,j).
//
// NUMERICS (calibrated over 5 rounds; the network amplifies activation error
// ~117x per layer):
//  * knots: jnp.linspace fp32 semantics K[m] = fl32(fl32(m)*fl32(1/67)),
//    ENDPOINT FORCED: K[67] = 1.0 exactly (jax sets last elem to `stop`;
//    fl32(67*fl32(1/67)) = 1.0000060 — R4's omission of this was a real bug
//    affecting all x in [0.9552, 1)).   [R4: np-style fp64-internal knots
//    2.8 -> jnp fp32 knots 0.56 — knots dominate; this is the validated model]
//  * basis: fp32 Cox-de Boor, reference expression tree, fp contraction OFF.
//  * einsum: fp64 accumulation (products of two fp32 are EXACT in fp64),
//    rounded to fp32 per activation => my activations are the correctly-
//    rounded true values given the fp32 basis; remaining distance to ref is
//    ref's own reduction-order noise only (minimum-expected-distance choice
//    since ref's partial-sum tree is unknowable).
//  * structure: one fused kernel, activations in LDS, zero workspace.

#define NBATCH 4096

// jnp.linspace(0,1,68,dtype=f32): delta = fl32(1/67); K[m] = fl32(m)*delta in
// fp32; endpoint forced to exactly 1.0f.
__device__ __forceinline__ float knotf(int m) {
    if (m == 67) return 1.0f;
    return (float)m * (1.0f / 67.0f);
}

// Bitwise replica of the reference Cox-de Boor recursion on the 7-wide
// nonzero window around span t.  Returns span t and w[r] = B_{t-3+r,3}(x),
// r=0..3.  Window entries whose basis index is outside [0,63] are finite
// garbage that provably never contaminates valid entries (they only feed
// strictly-lower-index garbage) — caller masks them.
__device__ __forceinline__ void basis4(float xf, int& t_out, float w[4]) {
#pragma clang fp contract(off)
    int t = (int)floorf(xf * 67.0f);
    t = t < 0 ? 0 : (t > 66 ? 66 : t);
    #pragma unroll
    for (int it = 0; it < 2; ++it) {   // enforce K[t] <= x < K[t+1] on fp32 knots
        if (t > 0 && xf < knotf(t)) --t;
        else if (t < 66 && xf >= knotf(t + 1)) ++t;
    }
    float W[7];
    #pragma unroll
    for (int j = 0; j < 7; ++j) W[j] = 0.0f;
    W[3] = 1.0f;   // degree-0 indicator at span t
    #pragma unroll
    for (int d = 1; d <= 3; ++d) {
        #pragma unroll
        for (int j = 0; j <= 6 - d; ++j) {
            const int k = t - 3 + j;
            const float ka = knotf(k);
            const float kb = knotf(k + d);
            const float kc = knotf(k + d + 1);
            const float ke = knotf(k + 1);
            const float lt = ((xf - ka) / (kb - ka)) * W[j];
            const float rt = ((kc - xf) / (kc - ke)) * W[j + 1];
            W[j] = lt + rt;
        }
    }
    t_out = t;
    w[0] = W[0]; w[1] = W[1]; w[2] = W[2]; w[3] = W[3];
}

// Basis for one activation value into the shared tables (st = -1 marks an
// out-of-range input whose basis row is all-zero -> contributes exactly 0).
__device__ __forceinline__ void stage1(float xf, float sw[4], int& st) {
    const bool inr = (xf >= 0.0f) && (xf < 1.0f);
    if (!inr) { st = -1; sw[0] = sw[1] = sw[2] = sw[3] = 0.0f; return; }
    int t; float w[4];
    basis4(xf, t, w);
    sw[0] = w[0]; sw[1] = w[1]; sw[2] = w[2]; sw[3] = w[3];
    st = t;
}

// fp64 gather-accumulate over all inputs for output j.  fp32*fp32 products
// are exact in fp64; the fp64 sum is order-insensitive to ~2^-52.  Guard
// k4 in [0,63] (guarded-out taps are zero in the reference; skipping exact).
template<int IN, int OUT>
__device__ __forceinline__ float gather_acc(const float* __restrict__ C, int j,
                                            const float (*__restrict__ sw)[4],
                                            const int* __restrict__ st) {
    double acc = 0.0;
    for (int i = 0; i < IN; ++i) {
        const int t = st[i];
        if (t < 0) continue;                       // wave-uniform (LDS broadcast)
        const float* Crow = C + ((size_t)i * OUT + j) * 64;
        #pragma unroll
        for (int r = 0; r < 4; ++r) {
            const int k4 = t - 3 + r;
            if (k4 >= 0 && k4 <= 63)
                acc += (double)sw[i][r] * (double)Crow[k4];
        }
    }
    return (float)acc;   // correctly-rounded fp32 activation
}

__global__ __launch_bounds__(256) void kan_fused(const float* __restrict__ x,
                                                 const float* __restrict__ C0,
                                                 const float* __restrict__ C1,
                                                 const float* __restrict__ C2,
                                                 float* __restrict__ out) {
    __shared__ float cur[256];
    __shared__ float sw[256][4];
    __shared__ int   st[256];
    const int b   = blockIdx.x;
    const int tid = threadIdx.x;

    // ---- layer 1: IN=64 -> OUT=256 ----
    if (tid < 64) stage1(x[(size_t)b * 64 + tid], sw[tid], st[tid]);
    __syncthreads();
    {
        const float a = gather_acc<64, 256>(C0, tid, sw, st);
        __syncthreads();                 // all stage-1 LDS reads done
        cur[tid] = a;                    // a1[b, tid]
    }
    __syncthreads();

    // ---- layer 2: IN=256 -> OUT=256 ----
    stage1(cur[tid], sw[tid], st[tid]);
    __syncthreads();
    {
        const float a = gather_acc<256, 256>(C1, tid, sw, st);
        __syncthreads();
        cur[tid] = a;                    // a2[b, tid]
    }
    __syncthreads();

    // ---- layer 3: IN=256 -> OUT=64 ----
    stage1(cur[tid], sw[tid], st[tid]);
    __syncthreads();
    if (tid < 64) {
        out[(size_t)b * 64 + tid] = gather_acc<256, 64>(C2, tid, sw, st);
    }
}

extern "C" void kernel_launch(void* const* d_in, const int* in_sizes, int n_in,
                              void* d_out, int out_size, void* d_ws, size_t ws_size,
                              hipStream_t stream) {
    const float* x  = (const float*)d_in[0];   // (4096, 64)
    const float* C0 = (const float*)d_in[1];   // (64, 256, 64)
    const float* C1 = (const float*)d_in[2];   // (256, 256, 64)
    const float* C2 = (const float*)d_in[3];   // (256, 64, 64)
    float* out = (float*)d_out;                // (4096, 64)

    kan_fused<<<NBATCH, 256, 0, stream>>>(x, C0, C1, C2, out);
}

// Round 7
// 711.032 us; speedup vs baseline: 2.7667x; 2.7667x over previous
//
#include <hip/hip_runtime.h>

// KAN forward: 3 layers of [deg-3 B-spline basis (64 bases) -> einsum 'bik,ijk->bj'].
// Only 4 basis values are nonzero per point => 4-tap gather per (i,j).
//
// NUMERICS (frozen from R6 — absmax sits exactly at threshold; output must
// stay bitwise-identical):
//  * knots: jnp.linspace fp32 semantics, endpoint forced to 1.0f
//  * basis: fp32 Cox-de Boor, reference expression tree, contraction OFF
//  * einsum: fp64 accumulation, per-(b,j) order = i ascending, r ascending
//    (fp32 products exact in fp64 => fma/mul equivalent; +/-0.0 adds exact)
//
// PERF (R6 postmortem): R6 was VMEM-request-bound on uncoalesced C gathers
// (1.07e9 stride-256B lane-loads ~= measured 1.95 ms). This version stages
// C[i][jtile][:] coalesced into LDS (XOR-swizzled [k][j] layout, b128-friendly)
// and gathers from LDS; basis w/t precomputed to workspace tables.

#define NBATCH 4096

// jnp.linspace(0,1,68,f32): delta = fl32(1/67); K[m] = fl32(m)*delta; K[67]=1.
__device__ __forceinline__ float knotf(int m) {
    if (m == 67) return 1.0f;
    return (float)m * (1.0f / 67.0f);
}

// Bitwise replica of the reference Cox-de Boor recursion on the 7-wide
// nonzero window around span t.  w[r] = B_{t-3+r,3}(x), r=0..3.
__device__ __forceinline__ void basis4(float xf, int& t_out, float w[4]) {
#pragma clang fp contract(off)
    int t = (int)floorf(xf * 67.0f);
    t = t < 0 ? 0 : (t > 66 ? 66 : t);
    #pragma unroll
    for (int it = 0; it < 2; ++it) {   // enforce K[t] <= x < K[t+1] on fp32 knots
        if (t > 0 && xf < knotf(t)) --t;
        else if (t < 66 && xf >= knotf(t + 1)) ++t;
    }
    float W[7];
    #pragma unroll
    for (int j = 0; j < 7; ++j) W[j] = 0.0f;
    W[3] = 1.0f;   // degree-0 indicator at span t
    #pragma unroll
    for (int d = 1; d <= 3; ++d) {
        #pragma unroll
        for (int j = 0; j <= 6 - d; ++j) {
            const int k = t - 3 + j;
            const float ka = knotf(k);
            const float kb = knotf(k + d);
            const float kc = knotf(k + d + 1);
            const float ke = knotf(k + 1);
            const float lt = ((xf - ka) / (kb - ka)) * W[j];
            const float rt = ((kc - xf) / (kc - ke)) * W[j + 1];
            W[j] = lt + rt;
        }
    }
    t_out = t;
    w[0] = W[0]; w[1] = W[1]; w[2] = W[2]; w[3] = W[3];
}

// ---------------- fast path: precompute basis tables + tiled gather ----------

// One thread per (i,b): write w[4] (OOB taps zeroed => branch-free gather;
// adding the resulting +/-0.0 products is bitwise-exact) and span t.
__global__ __launch_bounds__(256) void precomp_basis(const float* __restrict__ act,
        int IN, float4* __restrict__ wtab, int* __restrict__ ttab, int total) {
    int gid = blockIdx.x * 256 + threadIdx.x;
    if (gid >= total) return;
    const int i = gid >> 12;          // 4096 batch rows
    const int b = gid & 4095;
    const float xf = act[(size_t)b * IN + i];
    float w[4] = {0.f, 0.f, 0.f, 0.f};
    int t = 3;                        // safe span for all-zero rows
    if (xf >= 0.0f && xf < 1.0f) {
        basis4(xf, t, w);
        #pragma unroll
        for (int r = 0; r < 4; ++r) {
            const int k = t - 3 + r;
            if (k < 0 || k > 63) w[r] = 0.0f;   // matches R6's skip exactly
        }
    }
    wtab[gid] = make_float4(w[0], w[1], w[2], w[3]);
    ttab[gid] = t;
}

// Block = (64-wide j-tile) x (BT batch rows), 256 threads.
// Thread (q = tid&15, bsub = tid>>4) owns j-quad [jt*64+4q .. +3] and
// BPT = BT/16 batch rows.  Per i: stage C[i][jtile][:] (16 KB) coalesced into
// XOR-swizzled LDS [k][j] (element (k,jl) at word k*64 + (jl ^ (k&60)) --
// 16B-aligned quads, ~2-way banks both directions), double-buffered; gather
// 4 taps per (b) with one ds_read_b128 each (4 j at once); fp64 accumulate
// in i-asc, r-asc order (bitwise == R6).
template<int IN, int OUT, int BT>
__global__ __launch_bounds__(256) void kan_gather(const float* __restrict__ Cg,
        const float4* __restrict__ wtab, const int* __restrict__ ttab,
        float* __restrict__ aout) {
    constexpr int NJT = OUT / 64;
    constexpr int BPT = BT / 16;
    __shared__ __align__(16) float Cb[2][64 * 64];
    __shared__ __align__(16) float Wb[2][64][4];
    __shared__ int Tb[2][64];

    const int bid = blockIdx.x, tid = threadIdx.x;
    int jt, bblk;
    if (NJT == 4) {   // XCD-swizzle: blocks with equal bid%8 share an XCD & a j-slice
        jt = (bid & 7) >> 1;
        bblk = ((bid >> 3) << 1) | (bid & 1);
    } else {
        jt = 0; bblk = bid;
    }
    const int b0   = bblk * BT;
    const int kq   = tid & 15;        // staging role: k-quad
    const int jr0  = tid >> 4;        // staging role: j-row base
    const int q4   = (tid & 15) * 4;  // compute role: j-quad base
    const int bsub = tid >> 4;        // compute role: b subgroup

    double acc[BPT][4];
    #pragma unroll
    for (int bb = 0; bb < BPT; ++bb)
        #pragma unroll
        for (int jj = 0; jj < 4; ++jj) acc[bb][jj] = 0.0;

    auto stage = [&](int i2, int s) {
        const float* src = Cg + ((size_t)i2 * OUT + jt * 64) * 64;
        #pragma unroll
        for (int pass = 0; pass < 4; ++pass) {
            const int jl = jr0 + 16 * pass;
            const float4 v = *(const float4*)(src + (size_t)jl * 64 + kq * 4);
            const int base = (kq * 4) * 64 + (jl ^ (kq * 4));  // k=4kq+w rows
            Cb[s][base]       = v.x;
            Cb[s][base + 64]  = v.y;
            Cb[s][base + 128] = v.z;
            Cb[s][base + 192] = v.w;
        }
        if (tid < BT) {
            Wb[s][tid][0] = 0.0f;  // placate compiler aliasing; overwritten below
            *(float4*)&Wb[s][tid][0] = wtab[(size_t)i2 * 4096 + b0 + tid];
            Tb[s][tid] = ttab[(size_t)i2 * 4096 + b0 + tid];
        }
    };

    stage(0, 0);
    __syncthreads();
    for (int i = 0; i < IN; ++i) {
        const int s = i & 1;
        if (i + 1 < IN) stage(i + 1, s ^ 1);
        #pragma unroll
        for (int bb = 0; bb < BPT; ++bb) {
            const int bl = bsub * BPT + bb;
            const int t = Tb[s][bl];
            const float4 wv = *(const float4*)&Wb[s][bl][0];
            #pragma unroll
            for (int r = 0; r < 4; ++r) {
                int k = t - 3 + r;
                k = k < 0 ? 0 : (k > 63 ? 63 : k);   // w==0 where clamped
                const float4 c = *(const float4*)&Cb[s][k * 64 + (q4 ^ (k & 60))];
                const float wr = (r == 0) ? wv.x : (r == 1) ? wv.y : (r == 2) ? wv.z : wv.w;
                const double wd = (double)wr;
                acc[bb][0] += wd * (double)c.x;
                acc[bb][1] += wd * (double)c.y;
                acc[bb][2] += wd * (double)c.z;
                acc[bb][3] += wd * (double)c.w;
            }
        }
        __syncthreads();
    }

    #pragma unroll
    for (int bb = 0; bb < BPT; ++bb) {
        const int bl = bsub * BPT + bb;
        const float4 o = make_float4((float)acc[bb][0], (float)acc[bb][1],
                                     (float)acc[bb][2], (float)acc[bb][3]);
        *(float4*)(aout + (size_t)(b0 + bl) * OUT + jt * 64 + q4) = o;
    }
}

// ---------------- fallback: R6 monolithic kernel (proven green) -------------

__device__ __forceinline__ void stage1(float xf, float sw[4], int& st) {
    const bool inr = (xf >= 0.0f) && (xf < 1.0f);
    if (!inr) { st = -1; sw[0] = sw[1] = sw[2] = sw[3] = 0.0f; return; }
    int t; float w[4];
    basis4(xf, t, w);
    sw[0] = w[0]; sw[1] = w[1]; sw[2] = w[2]; sw[3] = w[3];
    st = t;
}

template<int IN, int OUT>
__device__ __forceinline__ float gather_acc(const float* __restrict__ C, int j,
                                            const float (*__restrict__ sw)[4],
                                            const int* __restrict__ st) {
    double acc = 0.0;
    for (int i = 0; i < IN; ++i) {
        const int t = st[i];
        if (t < 0) continue;
        const float* Crow = C + ((size_t)i * OUT + j) * 64;
        #pragma unroll
        for (int r = 0; r < 4; ++r) {
            const int k4 = t - 3 + r;
            if (k4 >= 0 && k4 <= 63)
                acc += (double)sw[i][r] * (double)Crow[k4];
        }
    }
    return (float)acc;
}

__global__ __launch_bounds__(256) void kan_fused(const float* __restrict__ x,
                                                 const float* __restrict__ C0,
                                                 const float* __restrict__ C1,
                                                 const float* __restrict__ C2,
                                                 float* __restrict__ out) {
    __shared__ float cur[256];
    __shared__ float sw[256][4];
    __shared__ int   st[256];
    const int b = blockIdx.x, tid = threadIdx.x;

    if (tid < 64) stage1(x[(size_t)b * 64 + tid], sw[tid], st[tid]);
    __syncthreads();
    {
        const float a = gather_acc<64, 256>(C0, tid, sw, st);
        __syncthreads();
        cur[tid] = a;
    }
    __syncthreads();

    stage1(cur[tid], sw[tid], st[tid]);
    __syncthreads();
    {
        const float a = gather_acc<256, 256>(C1, tid, sw, st);
        __syncthreads();
        cur[tid] = a;
    }
    __syncthreads();

    stage1(cur[tid], sw[tid], st[tid]);
    __syncthreads();
    if (tid < 64) out[(size_t)b * 64 + tid] = gather_acc<256, 64>(C2, tid, sw, st);
}

// ---------------- launcher --------------------------------------------------

extern "C" void kernel_launch(void* const* d_in, const int* in_sizes, int n_in,
                              void* d_out, int out_size, void* d_ws, size_t ws_size,
                              hipStream_t stream) {
    const float* x  = (const float*)d_in[0];   // (4096, 64)
    const float* C0 = (const float*)d_in[1];   // (64, 256, 64)
    const float* C1 = (const float*)d_in[2];   // (256, 256, 64)
    const float* C2 = (const float*)d_in[3];   // (256, 64, 64)
    float* out = (float*)d_out;                // (4096, 64)

    const size_t WTAB = (size_t)4096 * 256 * 16;   // 16.78 MB (float4 per (i,b))
    const size_t TTAB = (size_t)4096 * 256 * 4;    //  4.19 MB
    const size_t ACT  = (size_t)4096 * 256 * 4;    //  4.19 MB
    const size_t need = WTAB + TTAB + 2 * ACT;     // 29.36 MB

    if (ws_size >= need) {
        float4* wtab = (float4*)d_ws;
        int*    ttab = (int*)((char*)d_ws + WTAB);
        float*  a1   = (float*)((char*)d_ws + WTAB + TTAB);
        float*  a2   = a1 + (size_t)4096 * 256;

        precomp_basis<<<1024, 256, 0, stream>>>(x, 64, wtab, ttab, 64 * 4096);
        kan_gather<64, 256, 64><<<256, 256, 0, stream>>>(C0, wtab, ttab, a1);
        precomp_basis<<<4096, 256, 0, stream>>>(a1, 256, wtab, ttab, 256 * 4096);
        kan_gather<256, 256, 64><<<256, 256, 0, stream>>>(C1, wtab, ttab, a2);
        precomp_basis<<<4096, 256, 0, stream>>>(a2, 256, wtab, ttab, 256 * 4096);
        kan_gather<256, 64, 16><<<256, 256, 0, stream>>>(C2, wtab, ttab, out);
    } else {
        // workspace too small: proven-green monolithic path
        kan_fused<<<NBATCH, 256, 0, stream>>>(x, C0, C1, C2, out);
    }
}

// Round 8
// 636.064 us; speedup vs baseline: 3.0928x; 1.1179x over previous
//
#include <hip/hip_runtime.h>

// KAN forward: 3 layers of [deg-3 B-spline basis (64 bases) -> einsum 'bik,ijk->bj'].
// Only 4 basis values are nonzero per point => 4-tap gather per (i,j).
//
// NUMERICS (frozen since R6 — absmax sits exactly at threshold; per-(b,j)
// product set and fp64 add order must stay bitwise-identical):
//  * knots: jnp.linspace fp32 semantics, endpoint forced to 1.0f
//  * basis: fp32 Cox-de Boor, reference expression tree, contraction OFF
//  * einsum: fp64 accumulation, per-(b,j) order = i ascending, r ascending
//
// PERF history: R6 1967us (VMEM-request-bound L2 gathers) -> R7 711us
// (LDS-staged, but grid 256 = 1 block/CU, DS reads at ~12cyc/instr = 345us
// for layer 2).  R8: 32-wide j-tiles -> grid 512, 18.6KB LDS, 2+ blocks/CU;
// rotation swizzle (jq + k + (k>>3))&7 makes compute reads structurally
// conflict-free and staging writes 2-way (free).

#define NBATCH 4096

// jnp.linspace(0,1,68,f32): delta = fl32(1/67); K[m] = fl32(m)*delta; K[67]=1.
__device__ __forceinline__ float knotf(int m) {
    if (m == 67) return 1.0f;
    return (float)m * (1.0f / 67.0f);
}

// Bitwise replica of the reference Cox-de Boor recursion on the 7-wide
// nonzero window around span t.  w[r] = B_{t-3+r,3}(x), r=0..3.
__device__ __forceinline__ void basis4(float xf, int& t_out, float w[4]) {
#pragma clang fp contract(off)
    int t = (int)floorf(xf * 67.0f);
    t = t < 0 ? 0 : (t > 66 ? 66 : t);
    #pragma unroll
    for (int it = 0; it < 2; ++it) {   // enforce K[t] <= x < K[t+1] on fp32 knots
        if (t > 0 && xf < knotf(t)) --t;
        else if (t < 66 && xf >= knotf(t + 1)) ++t;
    }
    float W[7];
    #pragma unroll
    for (int j = 0; j < 7; ++j) W[j] = 0.0f;
    W[3] = 1.0f;   // degree-0 indicator at span t
    #pragma unroll
    for (int d = 1; d <= 3; ++d) {
        #pragma unroll
        for (int j = 0; j <= 6 - d; ++j) {
            const int k = t - 3 + j;
            const float ka = knotf(k);
            const float kb = knotf(k + d);
            const float kc = knotf(k + d + 1);
            const float ke = knotf(k + 1);
            const float lt = ((xf - ka) / (kb - ka)) * W[j];
            const float rt = ((kc - xf) / (kc - ke)) * W[j + 1];
            W[j] = lt + rt;
        }
    }
    t_out = t;
    w[0] = W[0]; w[1] = W[1]; w[2] = W[2]; w[3] = W[3];
}

// ---------------- precompute basis tables -----------------------------------

// One thread per (i,b): w[4] (OOB taps zeroed => branch-free gather; +/-0.0
// product adds are bitwise-exact no-ops) and span t.
__global__ __launch_bounds__(256) void precomp_basis(const float* __restrict__ act,
        int IN, float4* __restrict__ wtab, int* __restrict__ ttab, int total) {
    int gid = blockIdx.x * 256 + threadIdx.x;
    if (gid >= total) return;
    const int i = gid >> 12;          // 4096 batch rows
    const int b = gid & 4095;
    const float xf = act[(size_t)b * IN + i];
    float w[4] = {0.f, 0.f, 0.f, 0.f};
    int t = 3;                        // safe span for all-zero rows
    if (xf >= 0.0f && xf < 1.0f) {
        basis4(xf, t, w);
        #pragma unroll
        for (int r = 0; r < 4; ++r) {
            const int k = t - 3 + r;
            if (k < 0 || k > 63) w[r] = 0.0f;
        }
    }
    wtab[gid] = make_float4(w[0], w[1], w[2], w[3]);
    ttab[gid] = t;
}

// ---------------- 32-wide j-tile gather (layers 1 & 2) ----------------------
// Block = 32-wide j-tile x 64 batch rows, 256 threads, grid = 64*NJT.
// LDS slice layout (per i): word(k, jl) = k*32 + QP(jl>>2, k)*4 + (jl&3),
// QP(jq,k) = (jq + k + (k>>3)) & 7.  Reads: ds_read_b128 per (b,tap,j-quad),
// structurally conflict-free.  Writes: 2-way (free).  Double-buffered.
template<int IN, int OUT>
__global__ __launch_bounds__(256) void kan_gather32(const float* __restrict__ Cg,
        const float4* __restrict__ wtab, const int* __restrict__ ttab,
        float* __restrict__ aout) {
    constexpr int NJT = OUT / 32;
    __shared__ __align__(16) float Cb[2][64 * 32];
    __shared__ __align__(16) float Wb[2][64][4];
    __shared__ int Tb[2][64];

    const int bid = blockIdx.x, tid = threadIdx.x;
    // XCD swizzle: jt = bid % NJT -> each XCD's L2 holds one 2MB j-slice (NJT=8)
    const int jt   = bid % NJT;
    const int bblk = bid / NJT;
    const int b0   = bblk * 64;

    // staging roles: jl = tid>>3 (0..31), kq2 = tid&7 (two k-quads via pass)
    const int s_jl  = tid >> 3;
    const int s_kq2 = tid & 7;
    // compute roles: q = tid&7 (j-quad), bsub = tid>>3 (0..31), 2 b-rows each
    const int q    = tid & 7;
    const int bsub = tid >> 3;

    double acc[2][4];
    #pragma unroll
    for (int bb = 0; bb < 2; ++bb)
        #pragma unroll
        for (int jj = 0; jj < 4; ++jj) acc[bb][jj] = 0.0;

    auto stage = [&](int i2, int s) {
        const float* src = Cg + ((size_t)i2 * OUT + jt * 32) * 64;
        #pragma unroll
        for (int pass = 0; pass < 2; ++pass) {
            const int kq = s_kq2 + 8 * pass;       // k-quad 0..15
            const float4 v = *(const float4*)(src + (size_t)s_jl * 64 + kq * 4);
            const int jq = s_jl >> 2, jo = s_jl & 3;
            #pragma unroll
            for (int wi = 0; wi < 4; ++wi) {
                const int k = kq * 4 + wi;
                const int qp = (jq + k + (k >> 3)) & 7;
                Cb[s][k * 32 + qp * 4 + jo] = (wi == 0) ? v.x : (wi == 1) ? v.y
                                            : (wi == 2) ? v.z : v.w;
            }
        }
        if (tid < 64) {
            *(float4*)&Wb[s][tid][0] = wtab[(size_t)i2 * 4096 + b0 + tid];
            Tb[s][tid] = ttab[(size_t)i2 * 4096 + b0 + tid];
        }
    };

    stage(0, 0);
    __syncthreads();
    for (int i = 0; i < IN; ++i) {
        const int s = i & 1;
        if (i + 1 < IN) stage(i + 1, s ^ 1);
        #pragma unroll
        for (int bb = 0; bb < 2; ++bb) {
            const int bl = bsub * 2 + bb;
            const int t = Tb[s][bl];
            const float4 wv = *(const float4*)&Wb[s][bl][0];
            #pragma unroll
            for (int r = 0; r < 4; ++r) {
                int k = t - 3 + r;
                k = k < 0 ? 0 : (k > 63 ? 63 : k);   // w==0 where clamped
                const int qp = (q + k + (k >> 3)) & 7;
                const float4 c = *(const float4*)&Cb[s][k * 32 + qp * 4];
                const float wr = (r == 0) ? wv.x : (r == 1) ? wv.y : (r == 2) ? wv.z : wv.w;
                const double wd = (double)wr;
                acc[bb][0] += wd * (double)c.x;
                acc[bb][1] += wd * (double)c.y;
                acc[bb][2] += wd * (double)c.z;
                acc[bb][3] += wd * (double)c.w;
            }
        }
        __syncthreads();
    }

    #pragma unroll
    for (int bb = 0; bb < 2; ++bb) {
        const int bl = bsub * 2 + bb;
        const float4 o = make_float4((float)acc[bb][0], (float)acc[bb][1],
                                     (float)acc[bb][2], (float)acc[bb][3]);
        *(float4*)(aout + (size_t)(b0 + bl) * OUT + jt * 32 + q * 4) = o;
    }
}

// ---------------- 64-wide j-tile gather (layer 3, proven R7 path) -----------
template<int IN, int OUT, int BT>
__global__ __launch_bounds__(256) void kan_gather(const float* __restrict__ Cg,
        const float4* __restrict__ wtab, const int* __restrict__ ttab,
        float* __restrict__ aout) {
    constexpr int BPT = BT / 16;
    __shared__ __align__(16) float Cb[2][64 * 64];
    __shared__ __align__(16) float Wb[2][64][4];
    __shared__ int Tb[2][64];

    const int bid = blockIdx.x, tid = threadIdx.x;
    const int jt = 0, bblk = bid;
    const int b0   = bblk * BT;
    const int kq   = tid & 15;
    const int jr0  = tid >> 4;
    const int q4   = (tid & 15) * 4;
    const int bsub = tid >> 4;

    double acc[BPT][4];
    #pragma unroll
    for (int bb = 0; bb < BPT; ++bb)
        #pragma unroll
        for (int jj = 0; jj < 4; ++jj) acc[bb][jj] = 0.0;

    auto stage = [&](int i2, int s) {
        const float* src = Cg + ((size_t)i2 * OUT + jt * 64) * 64;
        #pragma unroll
        for (int pass = 0; pass < 4; ++pass) {
            const int jl = jr0 + 16 * pass;
            const float4 v = *(const float4*)(src + (size_t)jl * 64 + kq * 4);
            const int base = (kq * 4) * 64 + (jl ^ (kq * 4));
            Cb[s][base]       = v.x;
            Cb[s][base + 64]  = v.y;
            Cb[s][base + 128] = v.z;
            Cb[s][base + 192] = v.w;
        }
        if (tid < BT) {
            *(float4*)&Wb[s][tid][0] = wtab[(size_t)i2 * 4096 + b0 + tid];
            Tb[s][tid] = ttab[(size_t)i2 * 4096 + b0 + tid];
        }
    };

    stage(0, 0);
    __syncthreads();
    for (int i = 0; i < IN; ++i) {
        const int s = i & 1;
        if (i + 1 < IN) stage(i + 1, s ^ 1);
        #pragma unroll
        for (int bb = 0; bb < BPT; ++bb) {
            const int bl = bsub * BPT + bb;
            const int t = Tb[s][bl];
            const float4 wv = *(const float4*)&Wb[s][bl][0];
            #pragma unroll
            for (int r = 0; r < 4; ++r) {
                int k = t - 3 + r;
                k = k < 0 ? 0 : (k > 63 ? 63 : k);
                const float4 c = *(const float4*)&Cb[s][k * 64 + (q4 ^ (k & 60))];
                const float wr = (r == 0) ? wv.x : (r == 1) ? wv.y : (r == 2) ? wv.z : wv.w;
                const double wd = (double)wr;
                acc[bb][0] += wd * (double)c.x;
                acc[bb][1] += wd * (double)c.y;
                acc[bb][2] += wd * (double)c.z;
                acc[bb][3] += wd * (double)c.w;
            }
        }
        __syncthreads();
    }

    #pragma unroll
    for (int bb = 0; bb < BPT; ++bb) {
        const int bl = bsub * BPT + bb;
        const float4 o = make_float4((float)acc[bb][0], (float)acc[bb][1],
                                     (float)acc[bb][2], (float)acc[bb][3]);
        *(float4*)(aout + (size_t)(b0 + bl) * OUT + jt * 64 + q4) = o;
    }
}

// ---------------- fallback: R6 monolithic kernel (proven green) -------------

__device__ __forceinline__ void stage1(float xf, float sw[4], int& st) {
    const bool inr = (xf >= 0.0f) && (xf < 1.0f);
    if (!inr) { st = -1; sw[0] = sw[1] = sw[2] = sw[3] = 0.0f; return; }
    int t; float w[4];
    basis4(xf, t, w);
    sw[0] = w[0]; sw[1] = w[1]; sw[2] = w[2]; sw[3] = w[3];
    st = t;
}

template<int IN, int OUT>
__device__ __forceinline__ float gather_acc(const float* __restrict__ C, int j,
                                            const float (*__restrict__ sw)[4],
                                            const int* __restrict__ st) {
    double acc = 0.0;
    for (int i = 0; i < IN; ++i) {
        const int t = st[i];
        if (t < 0) continue;
        const float* Crow = C + ((size_t)i * OUT + j) * 64;
        #pragma unroll
        for (int r = 0; r < 4; ++r) {
            const int k4 = t - 3 + r;
            if (k4 >= 0 && k4 <= 63)
                acc += (double)sw[i][r] * (double)Crow[k4];
        }
    }
    return (float)acc;
}

__global__ __launch_bounds__(256) void kan_fused(const float* __restrict__ x,
                                                 const float* __restrict__ C0,
                                                 const float* __restrict__ C1,
                                                 const float* __restrict__ C2,
                                                 float* __restrict__ out) {
    __shared__ float cur[256];
    __shared__ float sw[256][4];
    __shared__ int   st[256];
    const int b = blockIdx.x, tid = threadIdx.x;

    if (tid < 64) stage1(x[(size_t)b * 64 + tid], sw[tid], st[tid]);
    __syncthreads();
    {
        const float a = gather_acc<64, 256>(C0, tid, sw, st);
        __syncthreads();
        cur[tid] = a;
    }
    __syncthreads();

    stage1(cur[tid], sw[tid], st[tid]);
    __syncthreads();
    {
        const float a = gather_acc<256, 256>(C1, tid, sw, st);
        __syncthreads();
        cur[tid] = a;
    }
    __syncthreads();

    stage1(cur[tid], sw[tid], st[tid]);
    __syncthreads();
    if (tid < 64) out[(size_t)b * 64 + tid] = gather_acc<256, 64>(C2, tid, sw, st);
}

// ---------------- launcher --------------------------------------------------

extern "C" void kernel_launch(void* const* d_in, const int* in_sizes, int n_in,
                              void* d_out, int out_size, void* d_ws, size_t ws_size,
                              hipStream_t stream) {
    const float* x  = (const float*)d_in[0];   // (4096, 64)
    const float* C0 = (const float*)d_in[1];   // (64, 256, 64)
    const float* C1 = (const float*)d_in[2];   // (256, 256, 64)
    const float* C2 = (const float*)d_in[3];   // (256, 64, 64)
    float* out = (float*)d_out;                // (4096, 64)

    const size_t WTAB = (size_t)4096 * 256 * 16;   // 16.78 MB (float4 per (i,b))
    const size_t TTAB = (size_t)4096 * 256 * 4;    //  4.19 MB
    const size_t ACT  = (size_t)4096 * 256 * 4;    //  4.19 MB
    const size_t need = WTAB + TTAB + 2 * ACT;     // 29.36 MB

    if (ws_size >= need) {
        float4* wtab = (float4*)d_ws;
        int*    ttab = (int*)((char*)d_ws + WTAB);
        float*  a1   = (float*)((char*)d_ws + WTAB + TTAB);
        float*  a2   = a1 + (size_t)4096 * 256;

        precomp_basis<<<1024, 256, 0, stream>>>(x, 64, wtab, ttab, 64 * 4096);
        kan_gather32<64, 256><<<512, 256, 0, stream>>>(C0, wtab, ttab, a1);
        precomp_basis<<<4096, 256, 0, stream>>>(a1, 256, wtab, ttab, 256 * 4096);
        kan_gather32<256, 256><<<512, 256, 0, stream>>>(C1, wtab, ttab, a2);
        precomp_basis<<<4096, 256, 0, stream>>>(a2, 256, wtab, ttab, 256 * 4096);
        kan_gather<256, 64, 16><<<256, 256, 0, stream>>>(C2, wtab, ttab, out);
    } else {
        kan_fused<<<NBATCH, 256, 0, stream>>>(x, C0, C1, C2, out);
    }
}

// Round 9
// 419.737 us; speedup vs baseline: 4.6867x; 1.5154x over previous
//
#include <hip/hip_runtime.h>

// KAN forward: 3 layers of [deg-3 B-spline basis (64 bases) -> einsum 'bik,ijk->bj'].
// Only 4 basis values are nonzero per point => 4-tap gather per (i,j).
//
// NUMERICS (frozen since R6 — absmax sits exactly at threshold; per-(b,j)
// product set and fp64 add order must stay bitwise-identical):
//  * knots: jnp.linspace fp32 semantics, endpoint forced to 1.0f
//  * basis: fp32 Cox-de Boor, reference expression tree, contraction OFF
//  * einsum: fp64 accumulation, per-(b,j) order = i ascending, k ascending
//    (fp32 products exact in fp64 => fma == mul+add; +/-0-product adds are
//    bitwise no-ops — validated R7/R8)
//
// PERF history: R6 1967us (VMEM-request-bound scalar gathers) -> R7 711
// (LDS-staged, grid 256) -> R8 636 (32-j tiles, grid 512; layer2 281us,
// DS-pipe + barrier-drain bound).  R9: NO LDS, NO BARRIERS — thread=(b,4j),
// wave spans 64 b => each C wave-load hits one 256B row (<=5 lines, L1-hot);
// taps made float4-contiguous via precomputed k0 + shift-aligned weights;
// activations stored transposed so precomp reads coalesce. grid 1024/layer.

#define NBATCH 4096

typedef float f4a __attribute__((ext_vector_type(4), aligned(4)));

// jnp.linspace(0,1,68,f32): delta = fl32(1/67); K[m] = fl32(m)*delta; K[67]=1.
__device__ __forceinline__ float knotf(int m) {
    if (m == 67) return 1.0f;
    return (float)m * (1.0f / 67.0f);
}

// Bitwise replica of the reference Cox-de Boor recursion on the 7-wide
// nonzero window around span t.  w[r] = B_{t-3+r,3}(x), r=0..3.
__device__ __forceinline__ void basis4(float xf, int& t_out, float w[4]) {
#pragma clang fp contract(off)
    int t = (int)floorf(xf * 67.0f);
    t = t < 0 ? 0 : (t > 66 ? 66 : t);
    #pragma unroll
    for (int it = 0; it < 2; ++it) {   // enforce K[t] <= x < K[t+1] on fp32 knots
        if (t > 0 && xf < knotf(t)) --t;
        else if (t < 66 && xf >= knotf(t + 1)) ++t;
    }
    float W[7];
    #pragma unroll
    for (int j = 0; j < 7; ++j) W[j] = 0.0f;
    W[3] = 1.0f;   // degree-0 indicator at span t
    #pragma unroll
    for (int d = 1; d <= 3; ++d) {
        #pragma unroll
        for (int j = 0; j <= 6 - d; ++j) {
            const int k = t - 3 + j;
            const float ka = knotf(k);
            const float kb = knotf(k + d);
            const float kc = knotf(k + d + 1);
            const float ke = knotf(k + 1);
            const float lt = ((xf - ka) / (kb - ka)) * W[j];
            const float rt = ((kc - xf) / (kc - ke)) * W[j + 1];
            W[j] = lt + rt;
        }
    }
    t_out = t;
    w[0] = W[0]; w[1] = W[1]; w[2] = W[2]; w[3] = W[3];
}

// ---------------- precompute: shift-aligned weights + k0 --------------------
// One thread per (i,b).  k0 = clamp(t-3, 0, 60); w'[m] applies to C[..][k0+m]
// with m-ascending == k-ascending == R6's r-ascending order; slots whose tap
// is OOB (or displaced by the clamp) get w'=0 — the resulting +/-0 products
// are bitwise-exact no-op adds (validated R7/R8).
__global__ __launch_bounds__(256) void precomp_basis(const float* __restrict__ act,
        int IN, int transposed, float4* __restrict__ wtab, int* __restrict__ ktab,
        int total) {
    int gid = blockIdx.x * 256 + threadIdx.x;
    if (gid >= total) return;
    const int i = gid >> 12;          // 4096 batch rows
    const int b = gid & 4095;
    const float xf = transposed ? act[gid] : act[(size_t)b * IN + i];
    float wp[4] = {0.f, 0.f, 0.f, 0.f};
    int k0 = 0;
    if (xf >= 0.0f && xf < 1.0f) {
        int t; float w[4];
        basis4(xf, t, w);
        k0 = t - 3;
        k0 = k0 < 0 ? 0 : (k0 > 60 ? 60 : k0);
        const int s = (t - 3) - k0;   // <0 iff t<3, >0 iff t>63, else 0
        #pragma unroll
        for (int m = 0; m < 4; ++m) {
            const int r = m - s;      // tap index; k = k0+m = t-3+r when valid
            wp[m] = (r >= 0 && r <= 3) ? w[r] : 0.0f;
        }
    }
    wtab[gid] = make_float4(wp[0], wp[1], wp[2], wp[3]);
    ktab[gid] = k0;
}

// ---------------- direct gather (no LDS, no barriers) -----------------------
// Block = 256 threads = 64 b-lanes x 4 j-threads; thread owns JPT consecutive
// j.  Wave = 64 b for ONE j-group => each C float4-load wave-instr lands in a
// single 256B C-row (<=5 lines, L1-hot: 4KB C + 1KB wtab working set per
// block-i).  wtab/ktab loads are perfectly coalesced (lane==b).  w/k0 for i+1
// prefetched while computing i (breaks the k0->C serial dependency).
template<int IN, int OUT, int JPT, bool TSTORE>
__global__ __launch_bounds__(256) void kan_direct(const float* __restrict__ Cg,
        const float4* __restrict__ wtab, const int* __restrict__ ktab,
        float* __restrict__ aout) {
    constexpr int JSPAN = 4 * JPT;
    constexpr int NJT = OUT / JSPAN;
    const int bid = blockIdx.x, tid = threadIdx.x;
    const int jt   = bid % NJT;       // XCD-swizzle: bid%8 groups share C j-slices
    const int bblk = bid / NJT;
    const int bl = tid & 63;
    const int jc = tid >> 6;
    const int j0 = jt * JSPAN + jc * JPT;
    const int b  = bblk * 64 + bl;

    double acc[JPT];
    #pragma unroll
    for (int m = 0; m < JPT; ++m) acc[m] = 0.0;

    float4 wv = wtab[b];
    int    kv = ktab[b];
    const float* Crow = Cg + (size_t)j0 * 64;   // advances by OUT*64 per i

    for (int i = 0; i < IN; ++i) {
        const float4 wcur = wv;
        const int    kcur = kv;
        if (i + 1 < IN) {                       // prefetch next i's w/k0
            wv = wtab[(size_t)(i + 1) * 4096 + b];
            kv = ktab[(size_t)(i + 1) * 4096 + b];
        }
        const float* base = Crow + kcur;
        const double w0 = (double)wcur.x, w1 = (double)wcur.y;
        const double w2 = (double)wcur.z, w3 = (double)wcur.w;
        #pragma unroll
        for (int m = 0; m < JPT; ++m) {
            const f4a c = *(const f4a*)(base + m * 64);
            acc[m] = fma(w0, (double)c.x, acc[m]);   // k ascending == R6 order
            acc[m] = fma(w1, (double)c.y, acc[m]);
            acc[m] = fma(w2, (double)c.z, acc[m]);
            acc[m] = fma(w3, (double)c.w, acc[m]);
        }
        Crow += (size_t)OUT * 64;
    }

    if (TSTORE) {   // transposed activation store aT[j][b] — b-coalesced
        #pragma unroll
        for (int m = 0; m < JPT; ++m)
            aout[(size_t)(j0 + m) * 4096 + b] = (float)acc[m];
    } else {        // final output: standard out[b][j]
        #pragma unroll
        for (int m = 0; m < JPT; ++m)
            aout[(size_t)b * OUT + j0 + m] = (float)acc[m];
    }
}

// ---------------- fallback: R6 monolithic kernel (proven green) -------------

__device__ __forceinline__ void stage1(float xf, float sw[4], int& st) {
    const bool inr = (xf >= 0.0f) && (xf < 1.0f);
    if (!inr) { st = -1; sw[0] = sw[1] = sw[2] = sw[3] = 0.0f; return; }
    int t; float w[4];
    basis4(xf, t, w);
    sw[0] = w[0]; sw[1] = w[1]; sw[2] = w[2]; sw[3] = w[3];
    st = t;
}

template<int IN, int OUT>
__device__ __forceinline__ float gather_acc(const float* __restrict__ C, int j,
                                            const float (*__restrict__ sw)[4],
                                            const int* __restrict__ st) {
    double acc = 0.0;
    for (int i = 0; i < IN; ++i) {
        const int t = st[i];
        if (t < 0) continue;
        const float* Crow = C + ((size_t)i * OUT + j) * 64;
        #pragma unroll
        for (int r = 0; r < 4; ++r) {
            const int k4 = t - 3 + r;
            if (k4 >= 0 && k4 <= 63)
                acc += (double)sw[i][r] * (double)Crow[k4];
        }
    }
    return (float)acc;
}

__global__ __launch_bounds__(256) void kan_fused(const float* __restrict__ x,
                                                 const float* __restrict__ C0,
                                                 const float* __restrict__ C1,
                                                 const float* __restrict__ C2,
                                                 float* __restrict__ out) {
    __shared__ float cur[256];
    __shared__ float sw[256][4];
    __shared__ int   st[256];
    const int b = blockIdx.x, tid = threadIdx.x;

    if (tid < 64) stage1(x[(size_t)b * 64 + tid], sw[tid], st[tid]);
    __syncthreads();
    {
        const float a = gather_acc<64, 256>(C0, tid, sw, st);
        __syncthreads();
        cur[tid] = a;
    }
    __syncthreads();

    stage1(cur[tid], sw[tid], st[tid]);
    __syncthreads();
    {
        const float a = gather_acc<256, 256>(C1, tid, sw, st);
        __syncthreads();
        cur[tid] = a;
    }
    __syncthreads();

    stage1(cur[tid], sw[tid], st[tid]);
    __syncthreads();
    if (tid < 64) out[(size_t)b * 64 + tid] = gather_acc<256, 64>(C2, tid, sw, st);
}

// ---------------- launcher --------------------------------------------------

extern "C" void kernel_launch(void* const* d_in, const int* in_sizes, int n_in,
                              void* d_out, int out_size, void* d_ws, size_t ws_size,
                              hipStream_t stream) {
    const float* x  = (const float*)d_in[0];   // (4096, 64)
    const float* C0 = (const float*)d_in[1];   // (64, 256, 64)
    const float* C1 = (const float*)d_in[2];   // (256, 256, 64)
    const float* C2 = (const float*)d_in[3];   // (256, 64, 64)
    float* out = (float*)d_out;                // (4096, 64)

    const size_t WTAB = (size_t)4096 * 256 * 16;   // 16.78 MB (float4 per (i,b))
    const size_t KTAB = (size_t)4096 * 256 * 4;    //  4.19 MB
    const size_t ACT  = (size_t)4096 * 256 * 4;    //  4.19 MB (transposed acts)
    const size_t need = WTAB + KTAB + 2 * ACT;     // 29.36 MB

    if (ws_size >= need) {
        float4* wtab = (float4*)d_ws;
        int*    ktab = (int*)((char*)d_ws + WTAB);
        float*  a1T  = (float*)((char*)d_ws + WTAB + KTAB);   // [256 i][4096 b]
        float*  a2T  = a1T + (size_t)4096 * 256;

        precomp_basis<<<1024, 256, 0, stream>>>(x, 64, 0, wtab, ktab, 64 * 4096);
        kan_direct<64, 256, 4, true><<<1024, 256, 0, stream>>>(C0, wtab, ktab, a1T);
        precomp_basis<<<4096, 256, 0, stream>>>(a1T, 256, 1, wtab, ktab, 256 * 4096);
        kan_direct<256, 256, 4, true><<<1024, 256, 0, stream>>>(C1, wtab, ktab, a2T);
        precomp_basis<<<4096, 256, 0, stream>>>(a2T, 256, 1, wtab, ktab, 256 * 4096);
        kan_direct<256, 64, 1, false><<<1024, 256, 0, stream>>>(C2, wtab, ktab, out);
    } else {
        kan_fused<<<NBATCH, 256, 0, stream>>>(x, C0, C1, C2, out);
    }
}